// Round 8
// baseline (190.467 us; speedup 1.0000x reference)
//
#include <hip/hip_runtime.h>
#include <hip/hip_bf16.h>
#include <math.h>

// Problem constants
#define B_ 64
#define L_ 256
#define H_ 1024
#define P_ 64
#define A_ 512
#define T_ 8
#define NSTEP 36

#define AS1 __attribute__((address_space(1)))
#define AS3 __attribute__((address_space(3)))

typedef __attribute__((ext_vector_type(8))) __bf16 bf16x8;
typedef __attribute__((ext_vector_type(4))) float f32x4;

__device__ __forceinline__ float bf2f(ushort u) {
  union { unsigned int i; float f; } v; v.i = ((unsigned int)u) << 16; return v.f;
}
__device__ __forceinline__ ushort f2bf_rne(float f) {
  union { float f; unsigned int i; } v; v.f = f;
  unsigned int r = v.i + 0x7FFFu + ((v.i >> 16) & 1u);  // RNE
  return (ushort)(r >> 16);
}
__device__ __forceinline__ unsigned int pack2_rne(float a, float b) {
  return (unsigned int)f2bf_rne(a) | ((unsigned int)f2bf_rne(b) << 16);
}

template <bool BF16>
__device__ __forceinline__ float ld1(const void* p, size_t i) {
  if (BF16) return bf2f(((const ushort*)p)[i]);
  return ((const float*)p)[i];
}
template <bool BF16>
__device__ __forceinline__ float2 ld2(const void* p, size_t i) {
  if (BF16) {
    ushort2 u = *(const ushort2*)((const ushort*)p + i);
    return (float2){bf2f(u.x), bf2f(u.y)};
  }
  return *(const float2*)((const float*)p + i);
}
template <bool BF16>
__device__ __forceinline__ float4 ld4(const void* p, size_t i) {
  if (BF16) {
    ushort4 u = *(const ushort4*)((const ushort*)p + i);
    return (float4){bf2f(u.x), bf2f(u.y), bf2f(u.z), bf2f(u.w)};
  }
  return *(const float4*)((const float*)p + i);
}

// Async global->LDS, 16B per lane. LDS dest = wave-uniform base + lane*16
// (m104 semantics); global source is per-lane (pre-swizzled, m173 pattern).
__device__ __forceinline__ void gll16(const void* g, void* l) {
  __builtin_amdgcn_global_load_lds((const AS1 void*)g, (AS3 void*)l, 16, 0, 0);
}

// Barrier without vmcnt drain (kept for the fp32 reg-staged kernel).
__device__ __forceinline__ void barrier_nodrain() {
  __builtin_amdgcn_sched_barrier(0);
  asm volatile("s_waitcnt lgkmcnt(0)" ::: "memory");
  __builtin_amdgcn_sched_barrier(0);
  __builtin_amdgcn_s_barrier();
  __builtin_amdgcn_sched_barrier(0);
}

// ---------------------------------------------------------------------------
// Kernel P: merged build_wts (blocks 0..575) + entity_features (576..639).
// ---------------------------------------------------------------------------
template <bool BF16>
__global__ __launch_bounds__(256) void prep_k(
    const void* __restrict__ wpos, ushort* __restrict__ WTs,
    const void* __restrict__ wh, const int* __restrict__ e1e,
    const int* __restrict__ e2e, const void* __restrict__ temb,
    float* __restrict__ EF) {
  if (blockIdx.x < 576) {
    __shared__ ushort tile[32][33];
    const int s  = blockIdx.x >> 4;   // 0..35 (k-step)
    const int at = blockIdx.x & 15;   // 0..15 (n tile of 32)
    const int tx = threadIdx.x & 31;
    const int ty = threadIdx.x >> 5;  // 0..7
#pragma unroll
    for (int i = 0; i < 4; ++i) {
      size_t idx = (size_t)(s * 32 + ty + i * 8) * A_ + at * 32 + tx;
      ushort u;
      if (BF16) u = ((const ushort*)wpos)[idx];
      else u = f2bf_rne(((const float*)wpos)[idx]);
      tile[ty + i * 8][tx] = u;
    }
    __syncthreads();
#pragma unroll
    for (int i = 0; i < 4; ++i) {
      WTs[(size_t)s * (A_ * 32) + (size_t)(at * 32 + ty + i * 8) * 32 + tx] =
          tile[tx][ty + i * 8];
    }
  } else {
    const int b = blockIdx.x - 576;
    const int tid = threadIdx.x;
    __shared__ float eh1[1024];
    __shared__ float eh2[1024];
    __shared__ float part[256][16];
    __shared__ float part2[16][17];
    __shared__ float scores[16];
    __shared__ float alpha[16];

    const size_t o1 = ((size_t)b * L_ + e1e[b]) * H_;
    const size_t o2 = ((size_t)b * L_ + e2e[b]) * H_;
    for (int h = tid; h < 1024; h += 256) {
      eh1[h] = ld1<BF16>(wh, o1 + h);
      eh2[h] = ld1<BF16>(wh, o2 + h);
    }
    __syncthreads();

    float p[16];
#pragma unroll
    for (int t = 0; t < 16; ++t) p[t] = 0.f;
    for (int h = tid; h < 1024; h += 256) {
      float a1 = eh1[h], a2 = eh2[h];
#pragma unroll
      for (int t = 0; t < 8; ++t) {
        float c = ld1<BF16>(temb, t * 1024 + h);
        p[t] += a1 * c;
        p[8 + t] += a2 * c;
      }
    }
#pragma unroll
    for (int t = 0; t < 16; ++t) part[tid][t] = p[t];
    __syncthreads();
    {
      const int t = tid & 15, j = tid >> 4;
      float s = 0.f;
#pragma unroll
      for (int i = 0; i < 16; ++i) s += part[j * 16 + i][t];
      part2[j][t] = s;
    }
    __syncthreads();
    if (tid < 16) {
      float s = 0.f;
#pragma unroll
      for (int i = 0; i < 16; ++i) s += part2[i][tid];
      scores[tid] = s;
    }
    __syncthreads();
    if (tid < 2) {
      const int base = tid * 8;
      float mx = scores[base];
      for (int t = 1; t < 8; ++t) mx = fmaxf(mx, scores[base + t]);
      float sum = 0.f;
      float e[8];
      for (int t = 0; t < 8; ++t) { e[t] = __expf(scores[base + t] - mx); sum += e[t]; }
      float inv = 1.f / sum;
      for (int t = 0; t < 8; ++t) alpha[base + t] = e[t] * inv;
    }
    __syncthreads();

    float* efb = EF + (size_t)b * 4096;
    for (int h = tid; h < 1024; h += 256) {
      float l1 = 0.f, l2 = 0.f;
#pragma unroll
      for (int t = 0; t < 8; ++t) {
        float c = ld1<BF16>(temb, t * 1024 + h);
        l1 += alpha[t] * c;
        l2 += alpha[8 + t] * c;
      }
      efb[h] = eh1[h];
      efb[1024 + h] = l1;
      efb[2048 + h] = eh2[h];
      efb[3072 + h] = l2;
    }
  }
}

// ---------------------------------------------------------------------------
// Kernel E2: dense_ent partials = EF[64,4096] @ W_ent[4096,512], k-split 32.
// grid 256 = kb(32) x nb(4) x mh(2). part [32][64][512] fp32, deterministic.
// ---------------------------------------------------------------------------
template <bool BF16>
__global__ __launch_bounds__(256) void ent_gemm(const float* __restrict__ EF,
                                                const void* __restrict__ went,
                                                float* __restrict__ part) {
  const int mh = blockIdx.x & 1;
  const int nb = (blockIdx.x >> 1) & 3;
  const int kb = blockIdx.x >> 3;
  const int tid = threadIdx.x;
  __shared__ float efs[32][128];

  const int k0 = kb * 128;
  {
    const int kq = (tid & 31) * 4;
    for (int m = tid >> 5; m < 32; m += 8) {
      *(float4*)&efs[m][kq] = *(const float4*)&EF[(size_t)(mh * 32 + m) * 4096 + k0 + kq];
    }
  }
  __syncthreads();

  const int n0 = nb * 128 + (tid & 31) * 4;
  const int mg = (tid >> 5) * 4;
  float acc[4][4];
#pragma unroll
  for (int i = 0; i < 4; ++i)
#pragma unroll
    for (int j = 0; j < 4; ++j) acc[i][j] = 0.f;

  for (int k = 0; k < 128; ++k) {
    float4 w = ld4<BF16>(went, (size_t)(k0 + k) * A_ + n0);
#pragma unroll
    for (int i = 0; i < 4; ++i) {
      float e = efs[mg + i][k];
      acc[i][0] += e * w.x;
      acc[i][1] += e * w.y;
      acc[i][2] += e * w.z;
      acc[i][3] += e * w.w;
    }
  }
#pragma unroll
  for (int i = 0; i < 4; ++i) {
    *(float4*)&part[((size_t)kb * 64 + mh * 32 + mg + i) * A_ + n0] =
        (float4){acc[i][0], acc[i][1], acc[i][2], acc[i][3]};
  }
}

// ---------------------------------------------------------------------------
// Kernel E3: dense_ent[64][512] = sum over 32 k-chunks of part. grid 128.
// (fp32 path only — the bf16 fused kernel folds this reduction in.)
// ---------------------------------------------------------------------------
__global__ __launch_bounds__(256) void ent_reduce(const float* __restrict__ part,
                                                  float* __restrict__ dense_ent) {
  const int idx = blockIdx.x * 256 + threadIdx.x;
  float s = 0.f;
#pragma unroll
  for (int kb = 0; kb < 32; ++kb) s += part[(size_t)kb * 32768 + idx];
  dense_ent[idx] = s;
}

// ---------------------------------------------------------------------------
// Kernel 4a (bf16): fused MFMA GEMM via global_load_lds staging (m97 pattern).
// BM=64, BN=128, BK=32, grid 1024, 4 blocks/CU, LDS ~25 KB.
// Staging: 3x gll16 per thread per step (A 16B, B 2x16B). LDS dest is LINEAR
// (wave base + lane*16); the XOR chunk swizzle is applied on the per-lane
// GLOBAL source address (rule #21: source permutation == read permutation;
// read offsets aoff/boff unchanged from the proven conflict-free layout).
// Double-buffer, one __syncthreads per step (its implicit vmcnt(0) IS the
// gll completion wait). No stage registers, no ds_writes, no reg round-trip.
// Also folds ent_reduce: dense_s[r] computed in prologue from `part`.
// ---------------------------------------------------------------------------
__global__ __launch_bounds__(256, 4) void fused_gemm_vu_bf16(
    const ushort* __restrict__ wh, const ushort* __restrict__ pe1,
    const ushort* __restrict__ pe2, const ushort* __restrict__ WTs,
    const float* __restrict__ part, const ushort* __restrict__ vvec,
    float* __restrict__ vu_part) {
  __shared__ __align__(16) ushort Abuf[2][2048];  // 4 KB each
  __shared__ __align__(16) ushort Bbuf[2][4096];  // 8 KB each
  __shared__ float vu_s[4][64];
  __shared__ float dense_s[64];

  const int tid = threadIdx.x;
  const int pid = blockIdx.x;
  const int wid = (pid & 7) * 128 + (pid >> 3);  // XCD-contiguous, bijective
  const int nb = wid & 3;            // n tile of 128
  const int mb = wid >> 2;           // 0..255
  const int rbase = mb * 64;
  const int wave = tid >> 6;
  const int lane = tid & 63;
  const int quad = lane >> 4;
  const int col = lane & 15;
  const int wr = wave >> 1;          // m half (32 rows)
  const int wc = wave & 1;           // n half (64 cols)

  // Fragment read offsets (ushort units): row*32 + (chunk^((row>>1)&3))*8
  int aoff[2], boff[4];
#pragma unroll
  for (int mf = 0; mf < 2; ++mf) {
    const int ra = wr * 32 + mf * 16 + col;
    aoff[mf] = ra * 32 + ((quad ^ ((ra >> 1) & 3)) << 3);
  }
#pragma unroll
  for (int nf = 0; nf < 4; ++nf) {
    const int rb = wc * 64 + nf * 16 + col;
    boff[nf] = rb * 32 + ((quad ^ ((rb >> 1) & 3)) << 3);
  }

  // Staging geometry: thread t fills LDS linear bytes t*16 -> (row=t>>2, c=t&3).
  // Source carries the inverse swizzle: chunk csw = c ^ sigma(row).
  // Note sigma(row+64) == sigma(row), so the same csw serves both B halves.
  const int srow = tid >> 2;
  const int csw = (((tid & 3) ^ ((srow >> 1) & 3)) << 3);  // ushort offset
  const ushort* aw  = wh  + (size_t)(rbase + srow) * H_ + csw;
  const ushort* ap1 = pe1 + (size_t)(rbase + srow) * P_ + csw;
  const ushort* ap2 = pe2 + (size_t)(rbase + srow) * P_ + csw;
  const ushort* b1  = WTs + (size_t)(nb * 128 + srow) * 32 + csw;
  const ushort* b2  = WTs + (size_t)(nb * 128 + 64 + srow) * 32 + csw;

  auto stage = [&](int buf, int s) {
    const ushort* as;
    if (s < 32)      as = aw + s * 32;
    else if (s < 34) as = ap1 + (s - 32) * 32;
    else             as = ap2 + (s - 34) * 32;
    const size_t so = (size_t)s * (A_ * 32);  // ushort stride per k-step
    gll16(as, &Abuf[buf][wave * 512]);
    gll16(b1 + so, &Bbuf[buf][wave * 512]);
    gll16(b2 + so, &Bbuf[buf][2048 + wave * 512]);
  };

  f32x4 acc[2][4];
#pragma unroll
  for (int i = 0; i < 2; ++i)
#pragma unroll
    for (int j = 0; j < 4; ++j) acc[i][j] = (f32x4){0.f, 0.f, 0.f, 0.f};

  // Prologue: fold ent_reduce (dense_ent rows this block needs) + stage step 0.
  const int bidx = rbase >> 8;
  float de = 0.f;
  if (tid < 64) {
    const int a = 2 * ((rbase & 255) + tid) + (nb >> 1);
#pragma unroll
    for (int kb = 0; kb < 32; ++kb)
      de += part[((size_t)kb * 64 + bidx) * A_ + a];
  }
  stage(0, 0);
  if (tid < 64) dense_s[tid] = de;
  __syncthreads();  // drains gll (vmcnt 0) + publishes dense_s

  int buf = 0;
  for (int s = 0; s < NSTEP; ++s) {
    if (s + 1 < NSTEP) stage(buf ^ 1, s + 1);
    const ushort* Ab = Abuf[buf];
    const ushort* Bb = Bbuf[buf];
    bf16x8 af[2], bfr[4];
#pragma unroll
    for (int mf = 0; mf < 2; ++mf) af[mf] = *(const bf16x8*)&Ab[aoff[mf]];
#pragma unroll
    for (int nf = 0; nf < 4; ++nf) bfr[nf] = *(const bf16x8*)&Bb[boff[nf]];
#pragma unroll
    for (int mf = 0; mf < 2; ++mf)
#pragma unroll
      for (int nf = 0; nf < 4; ++nf)
        acc[mf][nf] =
            __builtin_amdgcn_mfma_f32_16x16x32_bf16(af[mf], bfr[nf], acc[mf][nf], 0, 0, 0);
    __syncthreads();  // gll for s+1 complete + all waves done reading buf
    buf ^= 1;
  }

  // Epilogue: C/D layout col=lane&15 (n), row=quad*4+reg (m).
  float vv[4];
#pragma unroll
  for (int nf = 0; nf < 4; ++nf)
    vv[nf] = bf2f(vvec[nb * 128 + wc * 64 + nf * 16 + col]);

#pragma unroll
  for (int mf = 0; mf < 2; ++mf) {
    const int row0 = wr * 32 + mf * 16 + quad * 4;
    const float e0 = dense_s[row0 + 0];
    const float e1 = dense_s[row0 + 1];
    const float e2 = dense_s[row0 + 2];
    const float e3 = dense_s[row0 + 3];
    float s0 = 0.f, s1 = 0.f, s2 = 0.f, s3 = 0.f;
#pragma unroll
    for (int nf = 0; nf < 4; ++nf) {
      float vn = vv[nf];
      s0 += tanhf(acc[mf][nf][0] + e0) * vn;
      s1 += tanhf(acc[mf][nf][1] + e1) * vn;
      s2 += tanhf(acc[mf][nf][2] + e2) * vn;
      s3 += tanhf(acc[mf][nf][3] + e3) * vn;
    }
    s0 += __shfl_xor(s0, 1); s0 += __shfl_xor(s0, 2); s0 += __shfl_xor(s0, 4); s0 += __shfl_xor(s0, 8);
    s1 += __shfl_xor(s1, 1); s1 += __shfl_xor(s1, 2); s1 += __shfl_xor(s1, 4); s1 += __shfl_xor(s1, 8);
    s2 += __shfl_xor(s2, 1); s2 += __shfl_xor(s2, 2); s2 += __shfl_xor(s2, 4); s2 += __shfl_xor(s2, 8);
    s3 += __shfl_xor(s3, 1); s3 += __shfl_xor(s3, 2); s3 += __shfl_xor(s3, 4); s3 += __shfl_xor(s3, 8);
    if (col == 0) {
      vu_s[wave][row0 + 0] = s0;
      vu_s[wave][row0 + 1] = s1;
      vu_s[wave][row0 + 2] = s2;
      vu_s[wave][row0 + 3] = s3;
    }
  }
  __syncthreads();
  if (tid < 64) {
    const int wrr = tid >> 5;
    float s = vu_s[wrr * 2][tid] + vu_s[wrr * 2 + 1][tid];
    vu_part[(size_t)nb * (B_ * L_) + rbase + tid] = s;
  }
}

// ---------------------------------------------------------------------------
// Kernel 4b (fp32 input): R6's proven reg-staged kernel, fp32 path only.
// ---------------------------------------------------------------------------
__global__ __launch_bounds__(256, 4) void fused_gemm_vu_f32(
    const float* __restrict__ wh, const float* __restrict__ pe1,
    const float* __restrict__ pe2, const ushort* __restrict__ WTs,
    const float* __restrict__ dense_ent, const float* __restrict__ vvec,
    float* __restrict__ vu_part) {
  __shared__ __align__(16) ushort Abuf[2][64 * 32];
  __shared__ __align__(16) ushort Bbuf[2][128 * 32];
  __shared__ float vu_s[4][64];

  const int tid = threadIdx.x;
  const int pid = blockIdx.x;
  const int wid = (pid & 7) * 128 + (pid >> 3);
  const int nb = wid & 3;
  const int mb = wid >> 2;
  const int rbase = mb * 64;
  const int wave = tid >> 6;
  const int lane = tid & 63;
  const int quad = lane >> 4;
  const int col = lane & 15;
  const int wr = wave >> 1;
  const int wc = wave & 1;

  int aoff[2], boff[4];
#pragma unroll
  for (int mf = 0; mf < 2; ++mf) {
    const int ra = wr * 32 + mf * 16 + col;
    aoff[mf] = ra * 32 + ((quad ^ ((ra >> 1) & 3)) << 3);
  }
#pragma unroll
  for (int nf = 0; nf < 4; ++nf) {
    const int rb = wc * 64 + nf * 16 + col;
    boff[nf] = rb * 32 + ((quad ^ ((rb >> 1) & 3)) << 3);
  }

  const int brow = tid >> 1;
  const int bc0 = (tid & 1) * 2;
  const int sB0 = brow * 32 + ((bc0 ^ ((brow >> 1) & 3)) << 3);
  const size_t bsrc_off = (size_t)(nb * 128 + brow) * 32 + (size_t)(tid & 1) * 16;

  const int ar0 = tid >> 2, aq = tid & 3;
  const int sA0 = ar0 * 32 + ((aq ^ ((ar0 >> 1) & 3)) << 3);

  f32x4 acc[2][4];
#pragma unroll
  for (int i = 0; i < 2; ++i)
#pragma unroll
    for (int j = 0; j < 4; ++j) acc[i][j] = (f32x4){0.f, 0.f, 0.f, 0.f};

  float4 fXa, fXb; uint4 bX0, bX1;
  float4 fYa, fYb; uint4 bY0, bY1;

  auto ISSUE_X = [&](int s) {
    const float* src; int ld, k0;
    if (s < 32)      { src = wh;  ld = H_; k0 = s * 32; }
    else if (s < 34) { src = pe1; ld = P_; k0 = (s - 32) * 32; }
    else             { src = pe2; ld = P_; k0 = (s - 34) * 32; }
    const float* p0 = src + (size_t)(rbase + ar0) * ld + k0 + aq * 8;
    fXa = *(const float4*)p0;
    fXb = *(const float4*)(p0 + 4);
    const ushort* bs = WTs + (size_t)s * (A_ * 32) + bsrc_off;
    bX0 = *(const uint4*)bs;
    bX1 = *(const uint4*)(bs + 8);
  };
  auto ISSUE_Y = [&](int s) {
    const float* src; int ld, k0;
    if (s < 32)      { src = wh;  ld = H_; k0 = s * 32; }
    else if (s < 34) { src = pe1; ld = P_; k0 = (s - 32) * 32; }
    else             { src = pe2; ld = P_; k0 = (s - 34) * 32; }
    const float* p0 = src + (size_t)(rbase + ar0) * ld + k0 + aq * 8;
    fYa = *(const float4*)p0;
    fYb = *(const float4*)(p0 + 4);
    const ushort* bs = WTs + (size_t)s * (A_ * 32) + bsrc_off;
    bY0 = *(const uint4*)bs;
    bY1 = *(const uint4*)(bs + 8);
  };
  auto STORE_X = [&](int buf) {
    uint4 u0 = {pack2_rne(fXa.x, fXa.y), pack2_rne(fXa.z, fXa.w),
                pack2_rne(fXb.x, fXb.y), pack2_rne(fXb.z, fXb.w)};
    *(uint4*)&Abuf[buf][sA0] = u0;
    *(uint4*)&Bbuf[buf][sB0] = bX0;
    *(uint4*)&Bbuf[buf][sB0 ^ 8] = bX1;
  };
  auto STORE_Y = [&](int buf) {
    uint4 u0 = {pack2_rne(fYa.x, fYa.y), pack2_rne(fYa.z, fYa.w),
                pack2_rne(fYb.x, fYb.y), pack2_rne(fYb.z, fYb.w)};
    *(uint4*)&Abuf[buf][sA0] = u0;
    *(uint4*)&Bbuf[buf][sB0] = bY0;
    *(uint4*)&Bbuf[buf][sB0 ^ 8] = bY1;
  };
  auto COMPUTE = [&](int buf) {
    bf16x8 af[2], bfr[4];
#pragma unroll
    for (int mf = 0; mf < 2; ++mf) af[mf] = *(const bf16x8*)&Abuf[buf][aoff[mf]];
#pragma unroll
    for (int nf = 0; nf < 4; ++nf) bfr[nf] = *(const bf16x8*)&Bbuf[buf][boff[nf]];
#pragma unroll
    for (int mf = 0; mf < 2; ++mf)
#pragma unroll
      for (int nf = 0; nf < 4; ++nf)
        acc[mf][nf] =
            __builtin_amdgcn_mfma_f32_16x16x32_bf16(af[mf], bfr[nf], acc[mf][nf], 0, 0, 0);
  };

  ISSUE_X(0);
  ISSUE_Y(1);
  STORE_X(0);
  barrier_nodrain();

  for (int s = 0; s < NSTEP; s += 2) {
    if (s + 2 < NSTEP) ISSUE_X(s + 2);
    COMPUTE(0);
    STORE_Y(1);
    barrier_nodrain();
    if (s + 3 < NSTEP) ISSUE_Y(s + 3);
    COMPUTE(1);
    if (s + 2 < NSTEP) {
      STORE_X(0);
      barrier_nodrain();
    }
  }

  float vv[4];
#pragma unroll
  for (int nf = 0; nf < 4; ++nf)
    vv[nf] = vvec[nb * 128 + wc * 64 + nf * 16 + col];

#pragma unroll
  for (int mf = 0; mf < 2; ++mf) {
    const int row0 = wr * 32 + mf * 16 + quad * 4;
    const int r0 = rbase + row0;
    const int bidx = r0 >> 8;
    const int l0 = r0 & 255;
    const float* ebase = dense_ent + bidx * A_ + 2 * l0 + (nb >> 1);
    float e0 = ebase[0], e1 = ebase[2], e2 = ebase[4], e3 = ebase[6];
    float s0 = 0.f, s1 = 0.f, s2 = 0.f, s3 = 0.f;
#pragma unroll
    for (int nf = 0; nf < 4; ++nf) {
      float vn = vv[nf];
      s0 += tanhf(acc[mf][nf][0] + e0) * vn;
      s1 += tanhf(acc[mf][nf][1] + e1) * vn;
      s2 += tanhf(acc[mf][nf][2] + e2) * vn;
      s3 += tanhf(acc[mf][nf][3] + e3) * vn;
    }
    s0 += __shfl_xor(s0, 1); s0 += __shfl_xor(s0, 2); s0 += __shfl_xor(s0, 4); s0 += __shfl_xor(s0, 8);
    s1 += __shfl_xor(s1, 1); s1 += __shfl_xor(s1, 2); s1 += __shfl_xor(s1, 4); s1 += __shfl_xor(s1, 8);
    s2 += __shfl_xor(s2, 1); s2 += __shfl_xor(s2, 2); s2 += __shfl_xor(s2, 4); s2 += __shfl_xor(s2, 8);
    s3 += __shfl_xor(s3, 1); s3 += __shfl_xor(s3, 2); s3 += __shfl_xor(s3, 4); s3 += __shfl_xor(s3, 8);
    if (col == 0) {
      vu_s[wave][row0 + 0] = s0;
      vu_s[wave][row0 + 1] = s1;
      vu_s[wave][row0 + 2] = s2;
      vu_s[wave][row0 + 3] = s3;
    }
  }
  __syncthreads();
  if (tid < 64) {
    const int wrr = tid >> 5;
    float s = vu_s[wrr * 2][tid] + vu_s[wrr * 2 + 1][tid];
    vu_part[(size_t)nb * (B_ * L_) + rbase + tid] = s;
  }
}

// ---------------------------------------------------------------------------
// Kernel 5: per-b softmax over L, then z[b,h] = sum_l alpha[l] * wh[b,l,h]
// grid 128 = b*2 + hh; 2 h per thread via ushort2/float2 loads.
// ---------------------------------------------------------------------------
template <bool BF16>
__global__ __launch_bounds__(256) void softmax_z(const void* __restrict__ wh,
                                                 const float* __restrict__ vu_part,
                                                 void* __restrict__ out) {
  const int b = blockIdx.x >> 1;
  const int hh = blockIdx.x & 1;
  const int tid = threadIdx.x;
  __shared__ float alpha[256];
  __shared__ float red[256];

  float x = 0.f;
#pragma unroll
  for (int p = 0; p < 4; ++p) x += vu_part[(size_t)p * (B_ * L_) + b * L_ + tid];
  red[tid] = x;
  __syncthreads();
  for (int s = 128; s > 0; s >>= 1) {
    if (tid < s) red[tid] = fmaxf(red[tid], red[tid + s]);
    __syncthreads();
  }
  float m = red[0];
  __syncthreads();
  float e = __expf(x - m);
  red[tid] = e;
  __syncthreads();
  for (int s = 128; s > 0; s >>= 1) {
    if (tid < s) red[tid] += red[tid + s];
    __syncthreads();
  }
  alpha[tid] = e / red[0];
  __syncthreads();

  const int h0 = hh * 512 + tid * 2;
  const size_t base = (size_t)b * L_ * H_ + h0;
  float z0 = 0.f, z1 = 0.f;
  for (int l = 0; l < 256; l += 8) {
    float2 u0 = ld2<BF16>(wh, base + (size_t)(l + 0) * H_);
    float2 u1 = ld2<BF16>(wh, base + (size_t)(l + 1) * H_);
    float2 u2 = ld2<BF16>(wh, base + (size_t)(l + 2) * H_);
    float2 u3 = ld2<BF16>(wh, base + (size_t)(l + 3) * H_);
    float2 u4 = ld2<BF16>(wh, base + (size_t)(l + 4) * H_);
    float2 u5 = ld2<BF16>(wh, base + (size_t)(l + 5) * H_);
    float2 u6 = ld2<BF16>(wh, base + (size_t)(l + 6) * H_);
    float2 u7 = ld2<BF16>(wh, base + (size_t)(l + 7) * H_);
    float a0 = alpha[l + 0], a1 = alpha[l + 1], a2 = alpha[l + 2], a3 = alpha[l + 3];
    float a4 = alpha[l + 4], a5 = alpha[l + 5], a6 = alpha[l + 6], a7 = alpha[l + 7];
    z0 += a0 * u0.x + a1 * u1.x + a2 * u2.x + a3 * u3.x
        + a4 * u4.x + a5 * u5.x + a6 * u6.x + a7 * u7.x;
    z1 += a0 * u0.y + a1 * u1.y + a2 * u2.y + a3 * u3.y
        + a4 * u4.y + a5 * u5.y + a6 * u6.y + a7 * u7.y;
  }
  if (BF16) {
    ((unsigned int*)out)[((size_t)b * H_ + h0) >> 1] = pack2_rne(z0, z1);
  } else {
    *(float2*)((float*)out + (size_t)b * H_ + h0) = (float2){z0, z1};
  }
}

// ---------------------------------------------------------------------------
extern "C" void kernel_launch(void* const* d_in, const int* in_sizes, int n_in,
                              void* d_out, int out_size, void* d_ws, size_t ws_size,
                              hipStream_t stream) {
  const void* wh   = d_in[0];
  const void* pe1  = d_in[1];
  const void* pe2  = d_in[2];
  const int*  e1e  = (const int*)d_in[3];
  const int*  e2e  = (const int*)d_in[4];
  const void* temb = d_in[5];
  const void* wpos = d_in[6];
  const void* went = d_in[7];
  const void* vvec = d_in[8];

  const bool bf16 = (in_sizes[0] == (int)(B_ * L_ * H_ * 2));

  char* ws = (char*)d_ws;
  ushort* WTs      = (ushort*)ws;                  // 1,179,648 B
  float* dense_ent = (float*)(ws + 1179648);       // 131,072 B (fp32 path only)
  float* vu_part   = (float*)(ws + 1310720);       // 262,144 B (aliases EF head;
  float* EF        = (float*)(ws + 1310720);       //  EF dead before fused runs)
  float* part      = (float*)(ws + 2359296);       // 4,194,304 B

  if (bf16) {
    prep_k<true ><<<dim3(640), dim3(256), 0, stream>>>(wpos, WTs, wh, e1e, e2e, temb, EF);
    ent_gemm<true ><<<dim3(256), dim3(256), 0, stream>>>(EF, went, part);
    fused_gemm_vu_bf16<<<dim3(1024), dim3(256), 0, stream>>>(
        (const ushort*)wh, (const ushort*)pe1, (const ushort*)pe2, WTs, part,
        (const ushort*)vvec, vu_part);
    softmax_z<true ><<<dim3(128), dim3(256), 0, stream>>>(wh, vu_part, d_out);
  } else {
    prep_k<false><<<dim3(640), dim3(256), 0, stream>>>(wpos, WTs, wh, e1e, e2e, temb, EF);
    ent_gemm<false><<<dim3(256), dim3(256), 0, stream>>>(EF, went, part);
    ent_reduce<<<dim3(128), dim3(256), 0, stream>>>(part, dense_ent);
    fused_gemm_vu_f32<<<dim3(1024), dim3(256), 0, stream>>>(
        (const float*)wh, (const float*)pe1, (const float*)pe2, WTs, dense_ent,
        (const float*)vvec, vu_part);
    softmax_z<false><<<dim3(128), dim3(256), 0, stream>>>(wh, vu_part, d_out);
  }
}

// Round 9
// 187.089 us; speedup vs baseline: 1.0181x; 1.0181x over previous
//
#include <hip/hip_runtime.h>
#include <hip/hip_bf16.h>
#include <math.h>

// Problem constants
#define B_ 64
#define L_ 256
#define H_ 1024
#define P_ 64
#define A_ 512
#define T_ 8
#define NSTEP 36

#define AS1 __attribute__((address_space(1)))
#define AS3 __attribute__((address_space(3)))

typedef __attribute__((ext_vector_type(8))) __bf16 bf16x8;
typedef __attribute__((ext_vector_type(4))) float f32x4;

__device__ __forceinline__ float bf2f(ushort u) {
  union { unsigned int i; float f; } v; v.i = ((unsigned int)u) << 16; return v.f;
}
__device__ __forceinline__ ushort f2bf_rne(float f) {
  union { float f; unsigned int i; } v; v.f = f;
  unsigned int r = v.i + 0x7FFFu + ((v.i >> 16) & 1u);  // RNE
  return (ushort)(r >> 16);
}
__device__ __forceinline__ unsigned int pack2_rne(float a, float b) {
  return (unsigned int)f2bf_rne(a) | ((unsigned int)f2bf_rne(b) << 16);
}

template <bool BF16>
__device__ __forceinline__ float ld1(const void* p, size_t i) {
  if (BF16) return bf2f(((const ushort*)p)[i]);
  return ((const float*)p)[i];
}
template <bool BF16>
__device__ __forceinline__ float2 ld2(const void* p, size_t i) {
  if (BF16) {
    ushort2 u = *(const ushort2*)((const ushort*)p + i);
    return (float2){bf2f(u.x), bf2f(u.y)};
  }
  return *(const float2*)((const float*)p + i);
}
template <bool BF16>
__device__ __forceinline__ float4 ld4(const void* p, size_t i) {
  if (BF16) {
    ushort4 u = *(const ushort4*)((const ushort*)p + i);
    return (float4){bf2f(u.x), bf2f(u.y), bf2f(u.z), bf2f(u.w)};
  }
  return *(const float4*)((const float*)p + i);
}

// Async global->LDS, 16B per lane. LDS dest = wave-uniform base + lane*16;
// global source is per-lane (pre-swizzled, m173 pattern).
__device__ __forceinline__ void gll16(const void* g, void* l) {
  __builtin_amdgcn_global_load_lds((const AS1 void*)g, (AS3 void*)l, 16, 0, 0);
}

// Counted-vmcnt barriers (T4): vm2 leaves the 2 in-flight A-prefetch loads
// outstanding across the barrier; vm0 drains all (tail steps, no A prefetch).
__device__ __forceinline__ void bar_vm2() {
  __builtin_amdgcn_sched_barrier(0);
  asm volatile("s_waitcnt vmcnt(2) lgkmcnt(0)" ::: "memory");
  __builtin_amdgcn_sched_barrier(0);
  __builtin_amdgcn_s_barrier();
  __builtin_amdgcn_sched_barrier(0);
}
__device__ __forceinline__ void bar_vm0() {
  __builtin_amdgcn_sched_barrier(0);
  asm volatile("s_waitcnt vmcnt(0) lgkmcnt(0)" ::: "memory");
  __builtin_amdgcn_sched_barrier(0);
  __builtin_amdgcn_s_barrier();
  __builtin_amdgcn_sched_barrier(0);
}

// ---------------------------------------------------------------------------
// Kernel P: merged build_wts (blocks 0..575) + entity_features (576..639).
// ---------------------------------------------------------------------------
template <bool BF16>
__global__ __launch_bounds__(256) void prep_k(
    const void* __restrict__ wpos, ushort* __restrict__ WTs,
    const void* __restrict__ wh, const int* __restrict__ e1e,
    const int* __restrict__ e2e, const void* __restrict__ temb,
    float* __restrict__ EF) {
  if (blockIdx.x < 576) {
    __shared__ ushort tile[32][33];
    const int s  = blockIdx.x >> 4;   // 0..35 (k-step)
    const int at = blockIdx.x & 15;   // 0..15 (n tile of 32)
    const int tx = threadIdx.x & 31;
    const int ty = threadIdx.x >> 5;  // 0..7
#pragma unroll
    for (int i = 0; i < 4; ++i) {
      size_t idx = (size_t)(s * 32 + ty + i * 8) * A_ + at * 32 + tx;
      ushort u;
      if (BF16) u = ((const ushort*)wpos)[idx];
      else u = f2bf_rne(((const float*)wpos)[idx]);
      tile[ty + i * 8][tx] = u;
    }
    __syncthreads();
#pragma unroll
    for (int i = 0; i < 4; ++i) {
      WTs[(size_t)s * (A_ * 32) + (size_t)(at * 32 + ty + i * 8) * 32 + tx] =
          tile[tx][ty + i * 8];
    }
  } else {
    const int b = blockIdx.x - 576;
    const int tid = threadIdx.x;
    __shared__ float eh1[1024];
    __shared__ float eh2[1024];
    __shared__ float part[256][16];
    __shared__ float part2[16][17];
    __shared__ float scores[16];
    __shared__ float alpha[16];

    const size_t o1 = ((size_t)b * L_ + e1e[b]) * H_;
    const size_t o2 = ((size_t)b * L_ + e2e[b]) * H_;
    for (int h = tid; h < 1024; h += 256) {
      eh1[h] = ld1<BF16>(wh, o1 + h);
      eh2[h] = ld1<BF16>(wh, o2 + h);
    }
    __syncthreads();

    float p[16];
#pragma unroll
    for (int t = 0; t < 16; ++t) p[t] = 0.f;
    for (int h = tid; h < 1024; h += 256) {
      float a1 = eh1[h], a2 = eh2[h];
#pragma unroll
      for (int t = 0; t < 8; ++t) {
        float c = ld1<BF16>(temb, t * 1024 + h);
        p[t] += a1 * c;
        p[8 + t] += a2 * c;
      }
    }
#pragma unroll
    for (int t = 0; t < 16; ++t) part[tid][t] = p[t];
    __syncthreads();
    {
      const int t = tid & 15, j = tid >> 4;
      float s = 0.f;
#pragma unroll
      for (int i = 0; i < 16; ++i) s += part[j * 16 + i][t];
      part2[j][t] = s;
    }
    __syncthreads();
    if (tid < 16) {
      float s = 0.f;
#pragma unroll
      for (int i = 0; i < 16; ++i) s += part2[i][tid];
      scores[tid] = s;
    }
    __syncthreads();
    if (tid < 2) {
      const int base = tid * 8;
      float mx = scores[base];
      for (int t = 1; t < 8; ++t) mx = fmaxf(mx, scores[base + t]);
      float sum = 0.f;
      float e[8];
      for (int t = 0; t < 8; ++t) { e[t] = __expf(scores[base + t] - mx); sum += e[t]; }
      float inv = 1.f / sum;
      for (int t = 0; t < 8; ++t) alpha[base + t] = e[t] * inv;
    }
    __syncthreads();

    float* efb = EF + (size_t)b * 4096;
    for (int h = tid; h < 1024; h += 256) {
      float l1 = 0.f, l2 = 0.f;
#pragma unroll
      for (int t = 0; t < 8; ++t) {
        float c = ld1<BF16>(temb, t * 1024 + h);
        l1 += alpha[t] * c;
        l2 += alpha[8 + t] * c;
      }
      efb[h] = eh1[h];
      efb[1024 + h] = l1;
      efb[2048 + h] = eh2[h];
      efb[3072 + h] = l2;
    }
  }
}

// ---------------------------------------------------------------------------
// Kernel E2: dense_ent partials = EF[64,4096] @ W_ent[4096,512], k-split 32.
// grid 256 = kb(32) x nb(4) x mh(2). part [32][64][512] fp32, deterministic.
// ---------------------------------------------------------------------------
template <bool BF16>
__global__ __launch_bounds__(256) void ent_gemm(const float* __restrict__ EF,
                                                const void* __restrict__ went,
                                                float* __restrict__ part) {
  const int mh = blockIdx.x & 1;
  const int nb = (blockIdx.x >> 1) & 3;
  const int kb = blockIdx.x >> 3;
  const int tid = threadIdx.x;
  __shared__ float efs[32][128];

  const int k0 = kb * 128;
  {
    const int kq = (tid & 31) * 4;
    for (int m = tid >> 5; m < 32; m += 8) {
      *(float4*)&efs[m][kq] = *(const float4*)&EF[(size_t)(mh * 32 + m) * 4096 + k0 + kq];
    }
  }
  __syncthreads();

  const int n0 = nb * 128 + (tid & 31) * 4;
  const int mg = (tid >> 5) * 4;
  float acc[4][4];
#pragma unroll
  for (int i = 0; i < 4; ++i)
#pragma unroll
    for (int j = 0; j < 4; ++j) acc[i][j] = 0.f;

  for (int k = 0; k < 128; ++k) {
    float4 w = ld4<BF16>(went, (size_t)(k0 + k) * A_ + n0);
#pragma unroll
    for (int i = 0; i < 4; ++i) {
      float e = efs[mg + i][k];
      acc[i][0] += e * w.x;
      acc[i][1] += e * w.y;
      acc[i][2] += e * w.z;
      acc[i][3] += e * w.w;
    }
  }
#pragma unroll
  for (int i = 0; i < 4; ++i) {
    *(float4*)&part[((size_t)kb * 64 + mh * 32 + mg + i) * A_ + n0] =
        (float4){acc[i][0], acc[i][1], acc[i][2], acc[i][3]};
  }
}

// ---------------------------------------------------------------------------
// Kernel 4a (bf16 input path — kept for dtype robustness): R7 gll kernel.
// ---------------------------------------------------------------------------
__global__ __launch_bounds__(256, 4) void fused_gemm_vu_bf16(
    const ushort* __restrict__ wh, const ushort* __restrict__ pe1,
    const ushort* __restrict__ pe2, const ushort* __restrict__ WTs,
    const float* __restrict__ part, const ushort* __restrict__ vvec,
    float* __restrict__ vu_part) {
  __shared__ __align__(16) ushort Abuf[2][2048];
  __shared__ __align__(16) ushort Bbuf[2][4096];
  __shared__ float vu_s[4][64];
  __shared__ float dense_s[64];

  const int tid = threadIdx.x;
  const int pid = blockIdx.x;
  const int wid = (pid & 7) * 128 + (pid >> 3);
  const int nb = wid & 3;
  const int mb = wid >> 2;
  const int rbase = mb * 64;
  const int wave = tid >> 6;
  const int lane = tid & 63;
  const int quad = lane >> 4;
  const int col = lane & 15;
  const int wr = wave >> 1;
  const int wc = wave & 1;

  int aoff[2], boff[4];
#pragma unroll
  for (int mf = 0; mf < 2; ++mf) {
    const int ra = wr * 32 + mf * 16 + col;
    aoff[mf] = ra * 32 + ((quad ^ ((ra >> 1) & 3)) << 3);
  }
#pragma unroll
  for (int nf = 0; nf < 4; ++nf) {
    const int rb = wc * 64 + nf * 16 + col;
    boff[nf] = rb * 32 + ((quad ^ ((rb >> 1) & 3)) << 3);
  }

  const int srow = tid >> 2;
  const int csw = (((tid & 3) ^ ((srow >> 1) & 3)) << 3);
  const ushort* aw  = wh  + (size_t)(rbase + srow) * H_ + csw;
  const ushort* ap1 = pe1 + (size_t)(rbase + srow) * P_ + csw;
  const ushort* ap2 = pe2 + (size_t)(rbase + srow) * P_ + csw;
  const ushort* b1  = WTs + (size_t)(nb * 128 + srow) * 32 + csw;
  const ushort* b2  = WTs + (size_t)(nb * 128 + 64 + srow) * 32 + csw;

  auto stage = [&](int buf, int s) {
    const ushort* as;
    if (s < 32)      as = aw + s * 32;
    else if (s < 34) as = ap1 + (s - 32) * 32;
    else             as = ap2 + (s - 34) * 32;
    const size_t so = (size_t)s * (A_ * 32);
    gll16(as, &Abuf[buf][wave * 512]);
    gll16(b1 + so, &Bbuf[buf][wave * 512]);
    gll16(b2 + so, &Bbuf[buf][2048 + wave * 512]);
  };

  f32x4 acc[2][4];
#pragma unroll
  for (int i = 0; i < 2; ++i)
#pragma unroll
    for (int j = 0; j < 4; ++j) acc[i][j] = (f32x4){0.f, 0.f, 0.f, 0.f};

  const int bidx = rbase >> 8;
  float de = 0.f;
  if (tid < 64) {
    const int a = 2 * ((rbase & 255) + tid) + (nb >> 1);
#pragma unroll
    for (int kb = 0; kb < 32; ++kb)
      de += part[((size_t)kb * 64 + bidx) * A_ + a];
  }
  stage(0, 0);
  if (tid < 64) dense_s[tid] = de;
  __syncthreads();

  int buf = 0;
  for (int s = 0; s < NSTEP; ++s) {
    if (s + 1 < NSTEP) stage(buf ^ 1, s + 1);
    const ushort* Ab = Abuf[buf];
    const ushort* Bb = Bbuf[buf];
    bf16x8 af[2], bfr[4];
#pragma unroll
    for (int mf = 0; mf < 2; ++mf) af[mf] = *(const bf16x8*)&Ab[aoff[mf]];
#pragma unroll
    for (int nf = 0; nf < 4; ++nf) bfr[nf] = *(const bf16x8*)&Bb[boff[nf]];
#pragma unroll
    for (int mf = 0; mf < 2; ++mf)
#pragma unroll
      for (int nf = 0; nf < 4; ++nf)
        acc[mf][nf] =
            __builtin_amdgcn_mfma_f32_16x16x32_bf16(af[mf], bfr[nf], acc[mf][nf], 0, 0, 0);
    __syncthreads();
    buf ^= 1;
  }

  float vv[4];
#pragma unroll
  for (int nf = 0; nf < 4; ++nf)
    vv[nf] = bf2f(vvec[nb * 128 + wc * 64 + nf * 16 + col]);

#pragma unroll
  for (int mf = 0; mf < 2; ++mf) {
    const int row0 = wr * 32 + mf * 16 + quad * 4;
    const float e0 = dense_s[row0 + 0];
    const float e1 = dense_s[row0 + 1];
    const float e2 = dense_s[row0 + 2];
    const float e3 = dense_s[row0 + 3];
    float s0 = 0.f, s1 = 0.f, s2 = 0.f, s3 = 0.f;
#pragma unroll
    for (int nf = 0; nf < 4; ++nf) {
      float vn = vv[nf];
      s0 += tanhf(acc[mf][nf][0] + e0) * vn;
      s1 += tanhf(acc[mf][nf][1] + e1) * vn;
      s2 += tanhf(acc[mf][nf][2] + e2) * vn;
      s3 += tanhf(acc[mf][nf][3] + e3) * vn;
    }
    s0 += __shfl_xor(s0, 1); s0 += __shfl_xor(s0, 2); s0 += __shfl_xor(s0, 4); s0 += __shfl_xor(s0, 8);
    s1 += __shfl_xor(s1, 1); s1 += __shfl_xor(s1, 2); s1 += __shfl_xor(s1, 4); s1 += __shfl_xor(s1, 8);
    s2 += __shfl_xor(s2, 1); s2 += __shfl_xor(s2, 2); s2 += __shfl_xor(s2, 4); s2 += __shfl_xor(s2, 8);
    s3 += __shfl_xor(s3, 1); s3 += __shfl_xor(s3, 2); s3 += __shfl_xor(s3, 4); s3 += __shfl_xor(s3, 8);
    if (col == 0) {
      vu_s[wave][row0 + 0] = s0;
      vu_s[wave][row0 + 1] = s1;
      vu_s[wave][row0 + 2] = s2;
      vu_s[wave][row0 + 3] = s3;
    }
  }
  __syncthreads();
  if (tid < 64) {
    const int wrr = tid >> 5;
    float s = vu_s[wrr * 2][tid] + vu_s[wrr * 2 + 1][tid];
    vu_part[(size_t)nb * (B_ * L_) + rbase + tid] = s;
  }
}

// ---------------------------------------------------------------------------
// Kernel 4b (fp32 input — the path that actually runs):
// R9 change: B staged via global_load_lds (2x gll16/thread/step, linear LDS
// dest + pre-swizzled WTs source — same involution as read, rule #21);
// A keeps R5's proven X/Y 2-deep reg prefetch (fp32->bf16 pack required).
// Barrier = counted vmcnt: glls issued FIRST each phase (sched_barrier pins
// order), A-prefetch after; `s_waitcnt vmcnt(2) lgkmcnt(0)` retires the
// older glls and leaves the 2 A-loads in flight across the barrier (T4) —
// the thing __syncthreads/vmcnt(0) destroyed in R5/R6.
// Also folds ent_reduce into the prologue (dense_s, one fewer launch).
// ---------------------------------------------------------------------------
__global__ __launch_bounds__(256, 4) void fused_gemm_vu_f32(
    const float* __restrict__ wh, const float* __restrict__ pe1,
    const float* __restrict__ pe2, const ushort* __restrict__ WTs,
    const float* __restrict__ part, const float* __restrict__ vvec,
    float* __restrict__ vu_part) {
  __shared__ __align__(16) ushort Abuf[2][2048];  // A bf16 64x32, 4 KB each
  __shared__ __align__(16) ushort Bbuf[2][4096];  // B bf16 128x32, 8 KB each
  __shared__ float vu_s[4][64];
  __shared__ float dense_s[64];

  const int tid = threadIdx.x;
  const int pid = blockIdx.x;
  const int wid = (pid & 7) * 128 + (pid >> 3);  // XCD-contiguous, bijective
  const int nb = wid & 3;
  const int mb = wid >> 2;
  const int rbase = mb * 64;
  const int wave = tid >> 6;
  const int lane = tid & 63;
  const int quad = lane >> 4;
  const int col = lane & 15;
  const int wr = wave >> 1;
  const int wc = wave & 1;

  // Fragment read offsets (proven conflict-free)
  int aoff[2], boff[4];
#pragma unroll
  for (int mf = 0; mf < 2; ++mf) {
    const int ra = wr * 32 + mf * 16 + col;
    aoff[mf] = ra * 32 + ((quad ^ ((ra >> 1) & 3)) << 3);
  }
#pragma unroll
  for (int nf = 0; nf < 4; ++nf) {
    const int rb = wc * 64 + nf * 16 + col;
    boff[nf] = rb * 32 + ((quad ^ ((rb >> 1) & 3)) << 3);
  }

  // B gll staging: thread t -> LDS slot t (16B), rows srow / srow+64,
  // source chunk pre-swizzled (same involution as boff read).
  const int srow = tid >> 2;
  const int csw = (((tid & 3) ^ ((srow >> 1) & 3)) << 3);
  const ushort* b1 = WTs + (size_t)(nb * 128 + srow) * 32 + csw;
  const ushort* b2 = WTs + (size_t)(nb * 128 + 64 + srow) * 32 + csw;
  auto gllB = [&](int buf, int s) {
    const size_t so = (size_t)s * (A_ * 32);
    gll16(b1 + so, &Bbuf[buf][wave * 512]);
    gll16(b2 + so, &Bbuf[buf][2048 + wave * 512]);
  };

  // A reg staging (R5 pattern): row = tid>>2, chunk = tid&3, swizzled store.
  const int ar0 = tid >> 2, aq = tid & 3;
  const int sA0 = ar0 * 32 + ((aq ^ ((ar0 >> 1) & 3)) << 3);

  f32x4 acc[2][4];
#pragma unroll
  for (int i = 0; i < 2; ++i)
#pragma unroll
    for (int j = 0; j < 4; ++j) acc[i][j] = (f32x4){0.f, 0.f, 0.f, 0.f};

  float4 fXa, fXb;
  float4 fYa, fYb;

  auto ISSUE_X = [&](int s) {
    const float* src; int ld, k0;
    if (s < 32)      { src = wh;  ld = H_; k0 = s * 32; }
    else if (s < 34) { src = pe1; ld = P_; k0 = (s - 32) * 32; }
    else             { src = pe2; ld = P_; k0 = (s - 34) * 32; }
    const float* p0 = src + (size_t)(rbase + ar0) * ld + k0 + aq * 8;
    fXa = *(const float4*)p0;
    fXb = *(const float4*)(p0 + 4);
  };
  auto ISSUE_Y = [&](int s) {
    const float* src; int ld, k0;
    if (s < 32)      { src = wh;  ld = H_; k0 = s * 32; }
    else if (s < 34) { src = pe1; ld = P_; k0 = (s - 32) * 32; }
    else             { src = pe2; ld = P_; k0 = (s - 34) * 32; }
    const float* p0 = src + (size_t)(rbase + ar0) * ld + k0 + aq * 8;
    fYa = *(const float4*)p0;
    fYb = *(const float4*)(p0 + 4);
  };
  auto STORE_X = [&](int buf) {
    uint4 u0 = {pack2_rne(fXa.x, fXa.y), pack2_rne(fXa.z, fXa.w),
                pack2_rne(fXb.x, fXb.y), pack2_rne(fXb.z, fXb.w)};
    *(uint4*)&Abuf[buf][sA0] = u0;
  };
  auto STORE_Y = [&](int buf) {
    uint4 u0 = {pack2_rne(fYa.x, fYa.y), pack2_rne(fYa.z, fYa.w),
                pack2_rne(fYb.x, fYb.y), pack2_rne(fYb.z, fYb.w)};
    *(uint4*)&Abuf[buf][sA0] = u0;
  };
  auto COMPUTE = [&](int buf) {
    bf16x8 af[2], bfr[4];
#pragma unroll
    for (int mf = 0; mf < 2; ++mf) af[mf] = *(const bf16x8*)&Abuf[buf][aoff[mf]];
#pragma unroll
    for (int nf = 0; nf < 4; ++nf) bfr[nf] = *(const bf16x8*)&Bbuf[buf][boff[nf]];
#pragma unroll
    for (int mf = 0; mf < 2; ++mf)
#pragma unroll
      for (int nf = 0; nf < 4; ++nf)
        acc[mf][nf] =
            __builtin_amdgcn_mfma_f32_16x16x32_bf16(af[mf], bfr[nf], acc[mf][nf], 0, 0, 0);
  };

  // Prologue: fold ent_reduce + fill buffer 0. (One-time full drain.)
  const int bidx = rbase >> 8;
  float de = 0.f;
  if (tid < 64) {
    const int a = 2 * ((rbase & 255) + tid) + (nb >> 1);
#pragma unroll
    for (int kb = 0; kb < 32; ++kb)
      de += part[((size_t)kb * 64 + bidx) * A_ + a];
  }
  gllB(0, 0);
  ISSUE_X(0);
  ISSUE_Y(1);
  STORE_X(0);
  if (tid < 64) dense_s[tid] = de;
  __syncthreads();  // drains gll B(0) + publishes dense_s/Abuf[0]

  for (int s = 0; s < NSTEP; s += 2) {
    // half 1: compute step s (buf0); prep step s+1 (buf1)
    gllB(1, s + 1);                      // s+1 <= 35 always
    __builtin_amdgcn_sched_barrier(0);   // pin: glls issue before A loads
    if (s + 2 < NSTEP) ISSUE_X(s + 2);
    COMPUTE(0);
    STORE_Y(1);                          // compiler waits A_Y only (vmcnt leaves glls+A_X)
    if (s + 2 < NSTEP) bar_vm2(); else bar_vm0();
    // half 2: compute step s+1 (buf1); prep step s+2 (buf0)
    if (s + 2 < NSTEP) {
      gllB(0, s + 2);
      __builtin_amdgcn_sched_barrier(0);
      if (s + 3 < NSTEP) ISSUE_Y(s + 3);
    }
    COMPUTE(1);
    if (s + 2 < NSTEP) {
      STORE_X(0);
      if (s + 3 < NSTEP) bar_vm2(); else bar_vm0();
    }
  }

  // Epilogue: C/D layout col=lane&15 (n), row=quad*4+reg (m).
  float vv[4];
#pragma unroll
  for (int nf = 0; nf < 4; ++nf)
    vv[nf] = vvec[nb * 128 + wc * 64 + nf * 16 + col];

#pragma unroll
  for (int mf = 0; mf < 2; ++mf) {
    const int row0 = wr * 32 + mf * 16 + quad * 4;
    const float e0 = dense_s[row0 + 0];
    const float e1 = dense_s[row0 + 1];
    const float e2 = dense_s[row0 + 2];
    const float e3 = dense_s[row0 + 3];
    float s0 = 0.f, s1 = 0.f, s2 = 0.f, s3 = 0.f;
#pragma unroll
    for (int nf = 0; nf < 4; ++nf) {
      float vn = vv[nf];
      s0 += tanhf(acc[mf][nf][0] + e0) * vn;
      s1 += tanhf(acc[mf][nf][1] + e1) * vn;
      s2 += tanhf(acc[mf][nf][2] + e2) * vn;
      s3 += tanhf(acc[mf][nf][3] + e3) * vn;
    }
    s0 += __shfl_xor(s0, 1); s0 += __shfl_xor(s0, 2); s0 += __shfl_xor(s0, 4); s0 += __shfl_xor(s0, 8);
    s1 += __shfl_xor(s1, 1); s1 += __shfl_xor(s1, 2); s1 += __shfl_xor(s1, 4); s1 += __shfl_xor(s1, 8);
    s2 += __shfl_xor(s2, 1); s2 += __shfl_xor(s2, 2); s2 += __shfl_xor(s2, 4); s2 += __shfl_xor(s2, 8);
    s3 += __shfl_xor(s3, 1); s3 += __shfl_xor(s3, 2); s3 += __shfl_xor(s3, 4); s3 += __shfl_xor(s3, 8);
    if (col == 0) {
      vu_s[wave][row0 + 0] = s0;
      vu_s[wave][row0 + 1] = s1;
      vu_s[wave][row0 + 2] = s2;
      vu_s[wave][row0 + 3] = s3;
    }
  }
  __syncthreads();
  if (tid < 64) {
    const int wrr = tid >> 5;
    float s = vu_s[wrr * 2][tid] + vu_s[wrr * 2 + 1][tid];
    vu_part[(size_t)nb * (B_ * L_) + rbase + tid] = s;
  }
}

// ---------------------------------------------------------------------------
// Kernel 5: per-b softmax over L, then z[b,h] = sum_l alpha[l] * wh[b,l,h]
// grid 128 = b*2 + hh; 2 h per thread via ushort2/float2 loads.
// ---------------------------------------------------------------------------
template <bool BF16>
__global__ __launch_bounds__(256) void softmax_z(const void* __restrict__ wh,
                                                 const float* __restrict__ vu_part,
                                                 void* __restrict__ out) {
  const int b = blockIdx.x >> 1;
  const int hh = blockIdx.x & 1;
  const int tid = threadIdx.x;
  __shared__ float alpha[256];
  __shared__ float red[256];

  float x = 0.f;
#pragma unroll
  for (int p = 0; p < 4; ++p) x += vu_part[(size_t)p * (B_ * L_) + b * L_ + tid];
  red[tid] = x;
  __syncthreads();
  for (int s = 128; s > 0; s >>= 1) {
    if (tid < s) red[tid] = fmaxf(red[tid], red[tid + s]);
    __syncthreads();
  }
  float m = red[0];
  __syncthreads();
  float e = __expf(x - m);
  red[tid] = e;
  __syncthreads();
  for (int s = 128; s > 0; s >>= 1) {
    if (tid < s) red[tid] += red[tid + s];
    __syncthreads();
  }
  alpha[tid] = e / red[0];
  __syncthreads();

  const int h0 = hh * 512 + tid * 2;
  const size_t base = (size_t)b * L_ * H_ + h0;
  float z0 = 0.f, z1 = 0.f;
  for (int l = 0; l < 256; l += 8) {
    float2 u0 = ld2<BF16>(wh, base + (size_t)(l + 0) * H_);
    float2 u1 = ld2<BF16>(wh, base + (size_t)(l + 1) * H_);
    float2 u2 = ld2<BF16>(wh, base + (size_t)(l + 2) * H_);
    float2 u3 = ld2<BF16>(wh, base + (size_t)(l + 3) * H_);
    float2 u4 = ld2<BF16>(wh, base + (size_t)(l + 4) * H_);
    float2 u5 = ld2<BF16>(wh, base + (size_t)(l + 5) * H_);
    float2 u6 = ld2<BF16>(wh, base + (size_t)(l + 6) * H_);
    float2 u7 = ld2<BF16>(wh, base + (size_t)(l + 7) * H_);
    float a0 = alpha[l + 0], a1 = alpha[l + 1], a2 = alpha[l + 2], a3 = alpha[l + 3];
    float a4 = alpha[l + 4], a5 = alpha[l + 5], a6 = alpha[l + 6], a7 = alpha[l + 7];
    z0 += a0 * u0.x + a1 * u1.x + a2 * u2.x + a3 * u3.x
        + a4 * u4.x + a5 * u5.x + a6 * u6.x + a7 * u7.x;
    z1 += a0 * u0.y + a1 * u1.y + a2 * u2.y + a3 * u3.y
        + a4 * u4.y + a5 * u5.y + a6 * u6.y + a7 * u7.y;
  }
  if (BF16) {
    ((unsigned int*)out)[((size_t)b * H_ + h0) >> 1] = pack2_rne(z0, z1);
  } else {
    *(float2*)((float*)out + (size_t)b * H_ + h0) = (float2){z0, z1};
  }
}

// ---------------------------------------------------------------------------
extern "C" void kernel_launch(void* const* d_in, const int* in_sizes, int n_in,
                              void* d_out, int out_size, void* d_ws, size_t ws_size,
                              hipStream_t stream) {
  const void* wh   = d_in[0];
  const void* pe1  = d_in[1];
  const void* pe2  = d_in[2];
  const int*  e1e  = (const int*)d_in[3];
  const int*  e2e  = (const int*)d_in[4];
  const void* temb = d_in[5];
  const void* wpos = d_in[6];
  const void* went = d_in[7];
  const void* vvec = d_in[8];

  const bool bf16 = (in_sizes[0] == (int)(B_ * L_ * H_ * 2));

  char* ws = (char*)d_ws;
  ushort* WTs      = (ushort*)ws;                  // 1,179,648 B
  float* vu_part   = (float*)(ws + 1310720);       // 262,144 B (aliases EF head;
  float* EF        = (float*)(ws + 1310720);       //  EF dead before fused runs)
  float* part      = (float*)(ws + 2359296);       // 4,194,304 B

  if (bf16) {
    prep_k<true ><<<dim3(640), dim3(256), 0, stream>>>(wpos, WTs, wh, e1e, e2e, temb, EF);
    ent_gemm<true ><<<dim3(256), dim3(256), 0, stream>>>(EF, went, part);
    fused_gemm_vu_bf16<<<dim3(1024), dim3(256), 0, stream>>>(
        (const ushort*)wh, (const ushort*)pe1, (const ushort*)pe2, WTs, part,
        (const ushort*)vvec, vu_part);
    softmax_z<true ><<<dim3(128), dim3(256), 0, stream>>>(wh, vu_part, d_out);
  } else {
    prep_k<false><<<dim3(640), dim3(256), 0, stream>>>(wpos, WTs, wh, e1e, e2e, temb, EF);
    ent_gemm<false><<<dim3(256), dim3(256), 0, stream>>>(EF, went, part);
    fused_gemm_vu_f32<<<dim3(1024), dim3(256), 0, stream>>>(
        (const float*)wh, (const float*)pe1, (const float*)pe2, WTs, part,
        (const float*)vvec, vu_part);
    softmax_z<false><<<dim3(128), dim3(256), 0, stream>>>(wh, vu_part, d_out);
  }
}